// Round 2
// baseline (22292.859 us; speedup 1.0000x reference)
//
#include <hip/hip_runtime.h>

typedef unsigned short ushort;

__device__ __forceinline__ float b2f(ushort u) {
    unsigned int x = ((unsigned int)u) << 16;
    float f;
    __builtin_memcpy(&f, &x, 4);
    return f;
}
__device__ __forceinline__ ushort f2bf(float f) {
    unsigned int x;
    __builtin_memcpy(&x, &f, 4);
    unsigned int r = x + 0x7fffu + ((x >> 16) & 1u);
    return (ushort)(r >> 16);
}
__device__ __forceinline__ float ldf(const float* p) { return *p; }
__device__ __forceinline__ float ldf(const ushort* p) { return b2f(*p); }

#define NPIX 16384  // H*W = 128*128

// ---------------------------------------------------------------------------
// K1/K5: fused per-pixel LayerNorm(C=128) + 1x1 conv (GEMM W[O,128] @ xn[128,px])
// 64 pixels per block, 256 threads. Input dtype templated (x is f32, x2 is bf16).
// ---------------------------------------------------------------------------
template <int O, typename TIN>
__global__ __launch_bounds__(256) void ln_gemm(const TIN* __restrict__ xin,
                                               const float* __restrict__ W,
                                               const float* __restrict__ gamma,
                                               const float* __restrict__ beta,
                                               ushort* __restrict__ out) {
    __shared__ float xs[128][64];
    __shared__ ushort wc[128][64];  // transposed chunk: wc[k][o_local], bf16
    __shared__ float mu[64], rs[64];

    const int blk = blockIdx.x;
    const int b = blk >> 8;              // 256 tiles per batch image
    const int pix0 = (blk & 255) * 64;
    const int tid = threadIdx.x;

    const TIN* xb = xin + (size_t)b * 128 * NPIX + pix0;
    for (int i = tid; i < 128 * 64; i += 256) {
        int c = i >> 6, p = i & 63;
        xs[c][p] = ldf(&xb[(size_t)c * NPIX + p]);
    }
    __syncthreads();
    if (tid < 64) {
        float s = 0.f, ss = 0.f;
        for (int c = 0; c < 128; c++) {
            float v = xs[c][tid];
            s += v;
            ss += v * v;
        }
        float m = s * (1.f / 128.f);
        float var = ss * (1.f / 128.f) - m * m;
        mu[tid] = m;
        rs[tid] = rsqrtf(var + 1e-5f);
    }
    __syncthreads();
    for (int i = tid; i < 128 * 64; i += 256) {
        int c = i >> 6, p = i & 63;
        xs[c][p] = (xs[c][p] - mu[p]) * rs[p] * gamma[c] + beta[c];
    }

    const int oo = tid >> 6, p = tid & 63;
    for (int chunk = 0; chunk < O / 64; chunk++) {
        __syncthreads();
        for (int i = tid; i < 64 * 128; i += 256) {
            int ol = i >> 7, k = i & 127;
            wc[k][ol] = f2bf(W[(size_t)(chunk * 64 + ol) * 128 + k]);
        }
        __syncthreads();
        float acc[16];
#pragma unroll
        for (int j = 0; j < 16; j++) acc[j] = 0.f;
        for (int k = 0; k < 128; k++) {
            float xv = xs[k][p];
            const ushort* wr = &wc[k][oo * 16];
#pragma unroll
            for (int j = 0; j < 16; j++) acc[j] += b2f(wr[j]) * xv;
        }
#pragma unroll
        for (int j = 0; j < 16; j++) {
            int o = chunk * 64 + oo * 16 + j;
            out[((size_t)b * O + o) * NPIX + pix0 + p] = f2bf(acc[j]);
        }
    }
}

// ---------------------------------------------------------------------------
// K2/K6/K7: depthwise conv, zero padding. One thread per output element.
// in/out are bf16 intermediates, weights are f32 model params.
// ---------------------------------------------------------------------------
template <int KS>
__global__ __launch_bounds__(256) void dwconv(const ushort* __restrict__ in,
                                              const float* __restrict__ wdw,
                                              ushort* __restrict__ out, int CH) {
    size_t idx = (size_t)blockIdx.x * 256 + threadIdx.x;
    int xw = idx & 127;
    int y = (idx >> 7) & 127;
    size_t bc = idx >> 14;
    int c = (int)(bc % CH);
    const ushort* base = in + (bc << 14);
    const int P = KS / 2;
    float acc = 0.f;
#pragma unroll
    for (int dy = -P; dy <= P; dy++) {
        int yy = y + dy;
        if (yy < 0 || yy > 127) continue;
#pragma unroll
        for (int dx = -P; dx <= P; dx++) {
            int xx = xw + dx;
            if (xx < 0 || xx > 127) continue;
            acc += b2f(base[yy * 128 + xx]) * wdw[c * KS * KS + (dy + P) * KS + (dx + P)];
        }
    }
    out[idx] = f2bf(acc);
}

// ---------------------------------------------------------------------------
// K3a: L2 norms of q and k rows. One block per (b,h,d,qk) row of 16384.
// ---------------------------------------------------------------------------
__global__ __launch_bounds__(256) void l2norms(const ushort* __restrict__ qkv,
                                               float* __restrict__ norms) {
    int blk = blockIdx.x;
    int qk = blk & 1, d = (blk >> 1) & 15, h = (blk >> 5) & 7, b = blk >> 8;
    int ch = qk * 128 + h * 16 + d;
    const ushort* row = qkv + ((size_t)b * 384 + ch) * NPIX;
    float s = 0.f;
    for (int i = threadIdx.x; i < NPIX; i += 256) {
        float v = b2f(row[i]);
        s += v * v;
    }
    for (int off = 32; off; off >>= 1) s += __shfl_down(s, off, 64);
    __shared__ float red[4];
    if ((threadIdx.x & 63) == 0) red[threadIdx.x >> 6] = s;
    __syncthreads();
    if (threadIdx.x == 0) {
        float t = red[0] + red[1] + red[2] + red[3];
        norms[blk] = fmaxf(sqrtf(t), 1e-12f);
    }
}

// ---------------------------------------------------------------------------
// K3b: partial q·k^T dot products. 256 blocks = (b,h,seg of 4096 pixels).
// Each thread owns one (d,e) pair; Spart[seg][bh][d*16+e].
// ---------------------------------------------------------------------------
__global__ __launch_bounds__(256) void qk_partial(const ushort* __restrict__ qkv,
                                                  float* __restrict__ Spart) {
    __shared__ float qs[16][260], ks[16][260];
    int blk = blockIdx.x;
    int seg = blk & 3, h = (blk >> 2) & 7, b = blk >> 5;
    int bh = b * 8 + h;
    int n0 = seg * 4096;
    int tid = threadIdx.x;
    int d = tid >> 4, e = tid & 15;
    float acc = 0.f;
    for (int c0 = 0; c0 < 4096; c0 += 256) {
        __syncthreads();
        for (int i = tid; i < 16 * 256; i += 256) {
            int r = i >> 8, col = i & 255;
            qs[r][col] = b2f(qkv[((size_t)b * 384 + h * 16 + r) * NPIX + n0 + c0 + col]);
            ks[r][col] = b2f(qkv[((size_t)b * 384 + 128 + h * 16 + r) * NPIX + n0 + c0 + col]);
        }
        __syncthreads();
        for (int nn = 0; nn < 256; nn += 4) {
            float4 qv = *(const float4*)&qs[d][nn];
            float4 kv = *(const float4*)&ks[e][nn];
            acc += qv.x * kv.x + qv.y * kv.y + qv.z * kv.z + qv.w * kv.w;
        }
    }
    Spart[((size_t)seg * 64 + bh) * 256 + tid] = acc;
}

// ---------------------------------------------------------------------------
// K3c: reduce partials, normalize, softmax over e, fold attn into attn_proj:
//   M[b][o][h*16+e] = sum_d attn_proj[o][h*16+d] * attn[b,h,d,e]
// ---------------------------------------------------------------------------
__global__ __launch_bounds__(256) void softmax_M(const float* __restrict__ Spart,
                                                 const float* __restrict__ norms,
                                                 const float* __restrict__ temp,
                                                 const float* __restrict__ attn_proj,
                                                 float* __restrict__ M) {
    int bh = blockIdx.x;
    int b = bh >> 3, h = bh & 7;
    int tid = threadIdx.x;
    int d = tid >> 4, e = tid & 15;
    float s = Spart[(0 * 64 + bh) * 256 + tid] + Spart[(1 * 64 + bh) * 256 + tid] +
              Spart[(2 * 64 + bh) * 256 + tid] + Spart[(3 * 64 + bh) * 256 + tid];
    float nq = norms[((b * 8 + h) * 16 + d) * 2 + 0];
    float nk = norms[((b * 8 + h) * 16 + e) * 2 + 1];
    float logit = s / (nq * nk) * temp[h];
    float m = logit;
    for (int off = 8; off; off >>= 1) m = fmaxf(m, __shfl_xor(m, off, 64));
    float ex = expf(logit - m);
    float sum = ex;
    for (int off = 8; off; off >>= 1) sum += __shfl_xor(sum, off, 64);
    float attn = ex / sum;
    __shared__ float A[16][17];
    A[d][e] = attn;
    __syncthreads();
    for (int i = tid; i < 128 * 16; i += 256) {
        int o = i >> 4, ee = i & 15;
        float acc = 0.f;
#pragma unroll
        for (int dd = 0; dd < 16; dd++) acc += attn_proj[o * 128 + h * 16 + dd] * A[dd][ee];
        M[((size_t)b * 128 + o) * 128 + h * 16 + ee] = acc;
    }
}

// ---------------------------------------------------------------------------
// K4: x2 = x + M_b @ v   (per-pixel 128x128 GEMM, 64 px per block)
// x is the f32 model input; x2 stored bf16.
// ---------------------------------------------------------------------------
__global__ __launch_bounds__(256) void mv_residual(const ushort* __restrict__ qkv,
                                                   const float* __restrict__ M,
                                                   const float* __restrict__ x,
                                                   ushort* __restrict__ x2) {
    __shared__ ushort vs[128][64];
    __shared__ float mc[128][64];  // mc[k][o_local]
    int blk = blockIdx.x;
    int b = blk >> 8;
    int pix0 = (blk & 255) * 64;
    int tid = threadIdx.x;
    const ushort* vb = qkv + ((size_t)b * 384 + 256) * NPIX + pix0;
    for (int i = tid; i < 128 * 64; i += 256) {
        int c = i >> 6, p = i & 63;
        vs[c][p] = vb[(size_t)c * NPIX + p];
    }
    const int oo = tid >> 6, p = tid & 63;
    const float* Mb = M + (size_t)b * 128 * 128;
    for (int chunk = 0; chunk < 2; chunk++) {
        __syncthreads();
        for (int i = tid; i < 64 * 128; i += 256) {
            int ol = i >> 7, k = i & 127;
            mc[k][ol] = Mb[(size_t)(chunk * 64 + ol) * 128 + k];
        }
        __syncthreads();
        float acc[16];
#pragma unroll
        for (int j = 0; j < 16; j++) acc[j] = 0.f;
        for (int k = 0; k < 128; k++) {
            float vv = b2f(vs[k][p]);
            const float* mr = &mc[k][oo * 16];
#pragma unroll
            for (int j = 0; j < 16; j++) acc[j] += mr[j] * vv;
        }
#pragma unroll
        for (int j = 0; j < 16; j++) {
            int o = chunk * 64 + oo * 16 + j;
            size_t off = ((size_t)b * 128 + o) * NPIX + pix0 + p;
            x2[off] = f2bf(x[off] + acc[j]);
        }
    }
}

// ---------------------------------------------------------------------------
// K8: final GDFN epilogue: gated = [gelu(t*c1)*x3 ; gelu(t*c1)*x5] (512 ch),
//     out = x2 + pout[128,512] @ gated.  16 px per block. out is f32.
// ---------------------------------------------------------------------------
__global__ __launch_bounds__(256) void gdfn_final(const ushort* __restrict__ t,
                                                  const ushort* __restrict__ x3,
                                                  const ushort* __restrict__ x5,
                                                  const ushort* __restrict__ x2,
                                                  const float* __restrict__ c1w,
                                                  const float* __restrict__ pout,
                                                  float* __restrict__ out) {
    __shared__ ushort gs[512][16];  // gated, bf16
    __shared__ float wb[64][132];   // pout chunk transposed [k_local][o], padded
    int blk = blockIdx.x;
    int b = blk >> 10;  // 1024 tiles per batch image
    int pix0 = (blk & 1023) * 16;
    int tid = threadIdx.x;

    for (int i = tid; i < 256 * 16; i += 256) {
        int c = i >> 4, p = i & 15;
        size_t off = ((size_t)b * 256 + c) * NPIX + pix0 + p;
        float tv = b2f(t[off]);
        float x1 = tv * c1w[c];
        float g = 0.5f * x1 * (1.f + erff(x1 * 0.70710678118f));
        gs[c][p] = f2bf(g * b2f(x3[off]));
        gs[256 + c][p] = f2bf(g * b2f(x5[off]));
    }

    const int oo = tid >> 4, p = tid & 15;
    float acc[8];
#pragma unroll
    for (int j = 0; j < 8; j++) acc[j] = 0.f;

    for (int kb = 0; kb < 8; kb++) {
        __syncthreads();
        for (int i = tid; i < 64 * 128; i += 256) {
            int kk = i & 63, o = i >> 6;
            wb[kk][o] = pout[(size_t)o * 512 + kb * 64 + kk];
        }
        __syncthreads();
        for (int kk = 0; kk < 64; kk++) {
            float gv = b2f(gs[kb * 64 + kk][p]);
            const float* wr = &wb[kk][oo * 8];
#pragma unroll
            for (int j = 0; j < 8; j++) acc[j] += wr[j] * gv;
        }
    }
#pragma unroll
    for (int j = 0; j < 8; j++) {
        int o = oo * 8 + j;
        size_t off = ((size_t)b * 128 + o) * NPIX + pix0 + p;
        out[off] = b2f(x2[off]) + acc[j];
    }
}

// ---------------------------------------------------------------------------
extern "C" void kernel_launch(void* const* d_in, const int* in_sizes, int n_in,
                              void* d_out, int out_size, void* d_ws, size_t ws_size,
                              hipStream_t stream) {
    const float* x = (const float*)d_in[0];
    const float* ln1_w = (const float*)d_in[1];
    const float* ln1_b = (const float*)d_in[2];
    const float* qkv_w = (const float*)d_in[3];
    const float* qkv_dw = (const float*)d_in[4];
    const float* temperature = (const float*)d_in[5];
    const float* attn_proj = (const float*)d_in[6];
    const float* ln2_w = (const float*)d_in[7];
    const float* ln2_b = (const float*)d_in[8];
    const float* pin_w = (const float*)d_in[9];
    const float* c1_w = (const float*)d_in[10];
    const float* c3_w = (const float*)d_in[11];
    const float* c5_w = (const float*)d_in[12];
    const float* pout_w = (const float*)d_in[13];
    float* out = (float*)d_out;

    char* ws = (char*)d_ws;
    // workspace layout (bytes), lifetimes arranged so reuse is safe:
    ushort* qkv_pre = (ushort*)(ws + 0);            // 100,663,296  (dead after K2)
    ushort* qkv     = (ushort*)(ws + 100663296);    // 100,663,296  (dead after K4)
    ushort* x2      = (ushort*)(ws + 201326592);    //  33,554,432  (lives to end)
    ushort* t       = (ushort*)(ws + 0);            //  67,108,864  (reuses qkv_pre)
    ushort* x3      = (ushort*)(ws + 67108864);     //  67,108,864  (reuses tail+qkv)
    ushort* x5      = (ushort*)(ws + 134217728);    //  67,108,864  (reuses qkv)
    float*  norms   = (float*)(ws + 234881024);     //       8,192
    float*  Spart   = (float*)(ws + 234889216);     //     262,144
    float*  M       = (float*)(ws + 235151360);     //     524,288   (total ~235.7 MB)

    // K1: qkv_pre = qkv_w @ LN1(x)
    ln_gemm<384, float><<<2048, 256, 0, stream>>>(x, qkv_w, ln1_w, ln1_b, qkv_pre);
    // K2: qkv = dwconv3x3(qkv_pre)
    dwconv<3><<<196608, 256, 0, stream>>>(qkv_pre, qkv_dw, qkv, 384);
    // K3: attention (16x16 per head) folded into per-batch projection matrix M
    l2norms<<<2048, 256, 0, stream>>>(qkv, norms);
    qk_partial<<<256, 256, 0, stream>>>(qkv, Spart);
    softmax_M<<<64, 256, 0, stream>>>(Spart, norms, temperature, attn_proj, M);
    // K4: x2 = x + M_b @ v
    mv_residual<<<2048, 256, 0, stream>>>(qkv, M, x, x2);
    // K5: t = pin_w @ LN2(x2)
    ln_gemm<256, ushort><<<2048, 256, 0, stream>>>(x2, pin_w, ln2_w, ln2_b, t);
    // K6/K7: x3 = dw3x3(t), x5 = dw5x5(t)
    dwconv<3><<<131072, 256, 0, stream>>>(t, c3_w, x3, 256);
    dwconv<5><<<131072, 256, 0, stream>>>(t, c5_w, x5, 256);
    // K8: out = x2 + pout @ [gelu(t*c1)*x3 ; gelu(t*c1)*x5]
    gdfn_final<<<8192, 256, 0, stream>>>(t, x3, x5, x2, c1_w, pout_w, out);
}

// Round 3
// 2222.698 us; speedup vs baseline: 10.0296x; 10.0296x over previous
//
#include <hip/hip_runtime.h>

typedef unsigned short ushort;

__device__ __forceinline__ float b2f(ushort u) {
    unsigned int x = ((unsigned int)u) << 16;
    float f;
    __builtin_memcpy(&f, &x, 4);
    return f;
}
__device__ __forceinline__ ushort f2bf(float f) {
    unsigned int x;
    __builtin_memcpy(&x, &f, 4);
    unsigned int r = x + 0x7fffu + ((x >> 16) & 1u);
    return (ushort)(r >> 16);
}
__device__ __forceinline__ float u2f_lo(unsigned int u) {
    unsigned int x = u << 16;
    float f;
    __builtin_memcpy(&f, &x, 4);
    return f;
}
__device__ __forceinline__ float u2f_hi(unsigned int u) {
    unsigned int x = u & 0xffff0000u;
    float f;
    __builtin_memcpy(&f, &x, 4);
    return f;
}
__device__ __forceinline__ float ldf(const float* p) { return *p; }
__device__ __forceinline__ float ldf(const ushort* p) { return b2f(*p); }

#define NPIX 16384  // H*W = 128*128

// ---------------------------------------------------------------------------
// K1/K5: fused per-pixel LayerNorm(C=128) + 1x1 conv (GEMM W[O,128] @ xn[128,px])
// 64 pixels per block, 256 threads. Input dtype templated (x is f32, x2 is bf16).
// ---------------------------------------------------------------------------
template <int O, typename TIN>
__global__ __launch_bounds__(256) void ln_gemm(const TIN* __restrict__ xin,
                                               const float* __restrict__ W,
                                               const float* __restrict__ gamma,
                                               const float* __restrict__ beta,
                                               ushort* __restrict__ out) {
    __shared__ float xs[128][64];
    __shared__ ushort wc[128][64];  // transposed chunk: wc[k][o_local], bf16
    __shared__ float mu[64], rs[64];

    const int blk = blockIdx.x;
    const int b = blk >> 8;              // 256 tiles per batch image
    const int pix0 = (blk & 255) * 64;
    const int tid = threadIdx.x;

    const TIN* xb = xin + (size_t)b * 128 * NPIX + pix0;
    for (int i = tid; i < 128 * 64; i += 256) {
        int c = i >> 6, p = i & 63;
        xs[c][p] = ldf(&xb[(size_t)c * NPIX + p]);
    }
    __syncthreads();
    if (tid < 64) {
        float s = 0.f, ss = 0.f;
        for (int c = 0; c < 128; c++) {
            float v = xs[c][tid];
            s += v;
            ss += v * v;
        }
        float m = s * (1.f / 128.f);
        float var = ss * (1.f / 128.f) - m * m;
        mu[tid] = m;
        rs[tid] = rsqrtf(var + 1e-5f);
    }
    __syncthreads();
    for (int i = tid; i < 128 * 64; i += 256) {
        int c = i >> 6, p = i & 63;
        xs[c][p] = (xs[c][p] - mu[p]) * rs[p] * gamma[c] + beta[c];
    }

    const int oo = tid >> 6, p = tid & 63;
    for (int chunk = 0; chunk < O / 64; chunk++) {
        __syncthreads();
        for (int i = tid; i < 64 * 128; i += 256) {
            int ol = i >> 7, k = i & 127;
            wc[k][ol] = f2bf(W[(size_t)(chunk * 64 + ol) * 128 + k]);
        }
        __syncthreads();
        float acc[16];
#pragma unroll
        for (int j = 0; j < 16; j++) acc[j] = 0.f;
        for (int k = 0; k < 128; k++) {
            float xv = xs[k][p];
            const ushort* wr = &wc[k][oo * 16];
#pragma unroll
            for (int j = 0; j < 16; j++) acc[j] += b2f(wr[j]) * xv;
        }
#pragma unroll
        for (int j = 0; j < 16; j++) {
            int o = chunk * 64 + oo * 16 + j;
            out[((size_t)b * O + o) * NPIX + pix0 + p] = f2bf(acc[j]);
        }
    }
}

// ---------------------------------------------------------------------------
// K2/K6/K7: depthwise conv, zero padding. One thread per output element.
// in/out are bf16 intermediates, weights are f32 model params.
// ---------------------------------------------------------------------------
template <int KS>
__global__ __launch_bounds__(256) void dwconv(const ushort* __restrict__ in,
                                              const float* __restrict__ wdw,
                                              ushort* __restrict__ out, int CH) {
    size_t idx = (size_t)blockIdx.x * 256 + threadIdx.x;
    int xw = idx & 127;
    int y = (idx >> 7) & 127;
    size_t bc = idx >> 14;
    int c = (int)(bc % CH);
    const ushort* base = in + (bc << 14);
    const int P = KS / 2;
    float acc = 0.f;
#pragma unroll
    for (int dy = -P; dy <= P; dy++) {
        int yy = y + dy;
        if (yy < 0 || yy > 127) continue;
#pragma unroll
        for (int dx = -P; dx <= P; dx++) {
            int xx = xw + dx;
            if (xx < 0 || xx > 127) continue;
            acc += b2f(base[yy * 128 + xx]) * wdw[c * KS * KS + (dy + P) * KS + (dx + P)];
        }
    }
    out[idx] = f2bf(acc);
}

// ---------------------------------------------------------------------------
// K3a: L2 norms of q and k rows. One block per (b,h,d,qk) row of 16384.
// ---------------------------------------------------------------------------
__global__ __launch_bounds__(256) void l2norms(const ushort* __restrict__ qkv,
                                               float* __restrict__ norms) {
    int blk = blockIdx.x;
    int qk = blk & 1, d = (blk >> 1) & 15, h = (blk >> 5) & 7, b = blk >> 8;
    int ch = qk * 128 + h * 16 + d;
    const ushort* row = qkv + ((size_t)b * 384 + ch) * NPIX;
    float s = 0.f;
    for (int i = threadIdx.x; i < NPIX; i += 256) {
        float v = b2f(row[i]);
        s += v * v;
    }
    for (int off = 32; off; off >>= 1) s += __shfl_down(s, off, 64);
    __shared__ float red[4];
    if ((threadIdx.x & 63) == 0) red[threadIdx.x >> 6] = s;
    __syncthreads();
    if (threadIdx.x == 0) {
        float t = red[0] + red[1] + red[2] + red[3];
        norms[blk] = fmaxf(sqrtf(t), 1e-12f);
    }
}

// ---------------------------------------------------------------------------
// K3b: partial q·k^T dot products. 256 blocks = (b,h,seg of 4096 pixels).
// Each thread owns one (d,e) pair; Spart[seg][bh][d*16+e].
// ---------------------------------------------------------------------------
__global__ __launch_bounds__(256) void qk_partial(const ushort* __restrict__ qkv,
                                                  float* __restrict__ Spart) {
    __shared__ float qs[16][260], ks[16][260];
    int blk = blockIdx.x;
    int seg = blk & 3, h = (blk >> 2) & 7, b = blk >> 5;
    int bh = b * 8 + h;
    int n0 = seg * 4096;
    int tid = threadIdx.x;
    int d = tid >> 4, e = tid & 15;
    float acc = 0.f;
    for (int c0 = 0; c0 < 4096; c0 += 256) {
        __syncthreads();
        for (int i = tid; i < 16 * 256; i += 256) {
            int r = i >> 8, col = i & 255;
            qs[r][col] = b2f(qkv[((size_t)b * 384 + h * 16 + r) * NPIX + n0 + c0 + col]);
            ks[r][col] = b2f(qkv[((size_t)b * 384 + 128 + h * 16 + r) * NPIX + n0 + c0 + col]);
        }
        __syncthreads();
        for (int nn = 0; nn < 256; nn += 4) {
            float4 qv = *(const float4*)&qs[d][nn];
            float4 kv = *(const float4*)&ks[e][nn];
            acc += qv.x * kv.x + qv.y * kv.y + qv.z * kv.z + qv.w * kv.w;
        }
    }
    Spart[((size_t)seg * 64 + bh) * 256 + tid] = acc;
}

// ---------------------------------------------------------------------------
// K3c: reduce partials, normalize, softmax over e, fold attn into attn_proj:
//   M[b][o][h*16+e] = sum_d attn_proj[o][h*16+d] * attn[b,h,d,e]
// ---------------------------------------------------------------------------
__global__ __launch_bounds__(256) void softmax_M(const float* __restrict__ Spart,
                                                 const float* __restrict__ norms,
                                                 const float* __restrict__ temp,
                                                 const float* __restrict__ attn_proj,
                                                 float* __restrict__ M) {
    int bh = blockIdx.x;
    int b = bh >> 3, h = bh & 7;
    int tid = threadIdx.x;
    int d = tid >> 4, e = tid & 15;
    float s = Spart[(0 * 64 + bh) * 256 + tid] + Spart[(1 * 64 + bh) * 256 + tid] +
              Spart[(2 * 64 + bh) * 256 + tid] + Spart[(3 * 64 + bh) * 256 + tid];
    float nq = norms[((b * 8 + h) * 16 + d) * 2 + 0];
    float nk = norms[((b * 8 + h) * 16 + e) * 2 + 1];
    float logit = s / (nq * nk) * temp[h];
    float m = logit;
    for (int off = 8; off; off >>= 1) m = fmaxf(m, __shfl_xor(m, off, 64));
    float ex = expf(logit - m);
    float sum = ex;
    for (int off = 8; off; off >>= 1) sum += __shfl_xor(sum, off, 64);
    float attn = ex / sum;
    __shared__ float A[16][17];
    A[d][e] = attn;
    __syncthreads();
    for (int i = tid; i < 128 * 16; i += 256) {
        int o = i >> 4, ee = i & 15;
        float acc = 0.f;
#pragma unroll
        for (int dd = 0; dd < 16; dd++) acc += attn_proj[o * 128 + h * 16 + dd] * A[dd][ee];
        M[((size_t)b * 128 + o) * 128 + h * 16 + ee] = acc;
    }
}

// ---------------------------------------------------------------------------
// K4: x2 = x + M_b @ v   (per-pixel 128x128 GEMM, 64 px per block)
// x is the f32 model input; x2 stored bf16.
// ---------------------------------------------------------------------------
__global__ __launch_bounds__(256) void mv_residual(const ushort* __restrict__ qkv,
                                                   const float* __restrict__ M,
                                                   const float* __restrict__ x,
                                                   ushort* __restrict__ x2) {
    __shared__ ushort vs[128][64];
    __shared__ float mc[128][64];  // mc[k][o_local]
    int blk = blockIdx.x;
    int b = blk >> 8;
    int pix0 = (blk & 255) * 64;
    int tid = threadIdx.x;
    const ushort* vb = qkv + ((size_t)b * 384 + 256) * NPIX + pix0;
    for (int i = tid; i < 128 * 64; i += 256) {
        int c = i >> 6, p = i & 63;
        vs[c][p] = vb[(size_t)c * NPIX + p];
    }
    const int oo = tid >> 6, p = tid & 63;
    const float* Mb = M + (size_t)b * 128 * 128;
    for (int chunk = 0; chunk < 2; chunk++) {
        __syncthreads();
        for (int i = tid; i < 64 * 128; i += 256) {
            int ol = i >> 7, k = i & 127;
            mc[k][ol] = Mb[(size_t)(chunk * 64 + ol) * 128 + k];
        }
        __syncthreads();
        float acc[16];
#pragma unroll
        for (int j = 0; j < 16; j++) acc[j] = 0.f;
        for (int k = 0; k < 128; k++) {
            float vv = b2f(vs[k][p]);
            const float* mr = &mc[k][oo * 16];
#pragma unroll
            for (int j = 0; j < 16; j++) acc[j] += mr[j] * vv;
        }
#pragma unroll
        for (int j = 0; j < 16; j++) {
            int o = chunk * 64 + oo * 16 + j;
            size_t off = ((size_t)b * 128 + o) * NPIX + pix0 + p;
            x2[off] = f2bf(x[off] + acc[j]);
        }
    }
}

// ---------------------------------------------------------------------------
// K8 (REWRITTEN): out = x2 + pout[128,512] @ gated, gated computed per-chunk.
// 64 px per block, 256 threads = 8 o-groups x 32 px-pairs.
// Thread owns 16 o x 2 px -> acc[16][2] (32 VGPR). K in 8 chunks of 64:
//   stage gc[64ch][64px] (bf16, gelu(t*c1)*x3or5) + wb[64k][128o] (f32),
//   then MAC: per k: 1 ds_read_b32 (2 px) + 4 ds_read_b128 (16 w, broadcast)
//   + 32 fma. LDS 42 KB -> 3 blocks/CU.
// ---------------------------------------------------------------------------
__global__ __launch_bounds__(256) void gdfn_final(const ushort* __restrict__ t,
                                                  const ushort* __restrict__ x3,
                                                  const ushort* __restrict__ x5,
                                                  const ushort* __restrict__ x2,
                                                  const float* __restrict__ c1w,
                                                  const float* __restrict__ pout,
                                                  float* __restrict__ out) {
    __shared__ ushort gc[64][66];   // gated chunk, bf16, padded row (132 B)
    __shared__ float wb[64][132];   // weight chunk [k][o], padded row

    const int blk = blockIdx.x;
    const int b = blk >> 8;             // 256 tiles per image
    const int pix0 = (blk & 255) * 64;
    const int tid = threadIdx.x;
    const int og = tid >> 5;            // 0..7  (o group of 16)
    const int pp = tid & 31;            // 0..31 (pixel pair)

    float acc[16][2];
#pragma unroll
    for (int j = 0; j < 16; j++) acc[j][0] = acc[j][1] = 0.f;

    for (int kb = 0; kb < 8; kb++) {
        const ushort* xg = (kb < 4) ? x3 : x5;
        const int cbase = (kb & 3) * 64;
        __syncthreads();  // previous MAC done before overwriting gc/wb
        // stage gated chunk: 64 ch x 64 px
#pragma unroll 1
        for (int i = tid; i < 64 * 64; i += 256) {
            int c = i >> 6, p = i & 63;
            int ch = cbase + c;
            size_t off = ((size_t)b * 256 + ch) * NPIX + pix0 + p;
            float x1 = b2f(t[off]) * c1w[ch];
            float g = 0.5f * x1 * (1.f + erff(x1 * 0.70710678118f));
            gc[c][p] = f2bf(g * b2f(xg[off]));
        }
        // stage weight chunk: wb[kk][o] = pout[o*512 + kb*64 + kk]
#pragma unroll 1
        for (int i = tid; i < 64 * 128; i += 256) {
            int kk = i & 63, o = i >> 6;
            wb[kk][o] = pout[(size_t)o * 512 + kb * 64 + kk];
        }
        __syncthreads();
        // MAC over this chunk
        for (int kk = 0; kk < 64; kk++) {
            unsigned int pr = *(const unsigned int*)&gc[kk][pp * 2];
            float p0 = u2f_lo(pr), p1 = u2f_hi(pr);
            const float4* wr4 = (const float4*)&wb[kk][og * 16];
            float4 w0 = wr4[0], w1 = wr4[1], w2 = wr4[2], w3 = wr4[3];
            const float wv[16] = {w0.x, w0.y, w0.z, w0.w, w1.x, w1.y, w1.z, w1.w,
                                  w2.x, w2.y, w2.z, w2.w, w3.x, w3.y, w3.z, w3.w};
#pragma unroll
            for (int j = 0; j < 16; j++) {
                acc[j][0] += wv[j] * p0;
                acc[j][1] += wv[j] * p1;
            }
        }
    }
    // epilogue: out = x2 + acc
#pragma unroll
    for (int j = 0; j < 16; j++) {
        int o = og * 16 + j;
        size_t off = ((size_t)b * 128 + o) * NPIX + pix0 + pp * 2;
        out[off] = b2f(x2[off]) + acc[j][0];
        out[off + 1] = b2f(x2[off + 1]) + acc[j][1];
    }
}

// ---------------------------------------------------------------------------
extern "C" void kernel_launch(void* const* d_in, const int* in_sizes, int n_in,
                              void* d_out, int out_size, void* d_ws, size_t ws_size,
                              hipStream_t stream) {
    const float* x = (const float*)d_in[0];
    const float* ln1_w = (const float*)d_in[1];
    const float* ln1_b = (const float*)d_in[2];
    const float* qkv_w = (const float*)d_in[3];
    const float* qkv_dw = (const float*)d_in[4];
    const float* temperature = (const float*)d_in[5];
    const float* attn_proj = (const float*)d_in[6];
    const float* ln2_w = (const float*)d_in[7];
    const float* ln2_b = (const float*)d_in[8];
    const float* pin_w = (const float*)d_in[9];
    const float* c1_w = (const float*)d_in[10];
    const float* c3_w = (const float*)d_in[11];
    const float* c5_w = (const float*)d_in[12];
    const float* pout_w = (const float*)d_in[13];
    float* out = (float*)d_out;

    char* ws = (char*)d_ws;
    // workspace layout (bytes), lifetimes arranged so reuse is safe:
    ushort* qkv_pre = (ushort*)(ws + 0);            // 100,663,296  (dead after K2)
    ushort* qkv     = (ushort*)(ws + 100663296);    // 100,663,296  (dead after K4)
    ushort* x2      = (ushort*)(ws + 201326592);    //  33,554,432  (lives to end)
    ushort* t       = (ushort*)(ws + 0);            //  67,108,864  (reuses qkv_pre)
    ushort* x3      = (ushort*)(ws + 67108864);     //  67,108,864  (reuses tail+qkv)
    ushort* x5      = (ushort*)(ws + 134217728);    //  67,108,864  (reuses qkv)
    float*  norms   = (float*)(ws + 234881024);     //       8,192
    float*  Spart   = (float*)(ws + 234889216);     //     262,144
    float*  M       = (float*)(ws + 235151360);     //     524,288   (total ~235.7 MB)

    // K1: qkv_pre = qkv_w @ LN1(x)
    ln_gemm<384, float><<<2048, 256, 0, stream>>>(x, qkv_w, ln1_w, ln1_b, qkv_pre);
    // K2: qkv = dwconv3x3(qkv_pre)
    dwconv<3><<<196608, 256, 0, stream>>>(qkv_pre, qkv_dw, qkv, 384);
    // K3: attention (16x16 per head) folded into per-batch projection matrix M
    l2norms<<<2048, 256, 0, stream>>>(qkv, norms);
    qk_partial<<<256, 256, 0, stream>>>(qkv, Spart);
    softmax_M<<<64, 256, 0, stream>>>(Spart, norms, temperature, attn_proj, M);
    // K4: x2 = x + M_b @ v
    mv_residual<<<2048, 256, 0, stream>>>(qkv, M, x, x2);
    // K5: t = pin_w @ LN2(x2)
    ln_gemm<256, ushort><<<2048, 256, 0, stream>>>(x2, pin_w, ln2_w, ln2_b, t);
    // K6/K7: x3 = dw3x3(t), x5 = dw5x5(t)
    dwconv<3><<<131072, 256, 0, stream>>>(t, c3_w, x3, 256);
    dwconv<5><<<131072, 256, 0, stream>>>(t, c5_w, x5, 256);
    // K8: out = x2 + pout @ [gelu(t*c1)*x3 ; gelu(t*c1)*x5]
    gdfn_final<<<2048, 256, 0, stream>>>(t, x3, x5, x2, c1_w, pout_w, out);
}

// Round 4
// 1217.643 us; speedup vs baseline: 18.3082x; 1.8254x over previous
//
#include <hip/hip_runtime.h>

typedef unsigned short ushort;
typedef __bf16 bf16x8 __attribute__((ext_vector_type(8)));
typedef unsigned short ushort8v __attribute__((ext_vector_type(8)));
typedef float f32x4 __attribute__((ext_vector_type(4)));

__device__ __forceinline__ float b2f(ushort u) {
    unsigned int x = ((unsigned int)u) << 16;
    float f;
    __builtin_memcpy(&f, &x, 4);
    return f;
}
__device__ __forceinline__ ushort f2bf(float f) {
    unsigned int x;
    __builtin_memcpy(&x, &f, 4);
    unsigned int r = x + 0x7fffu + ((x >> 16) & 1u);
    return (ushort)(r >> 16);
}
__device__ __forceinline__ ushort to_bf(float f) { return f2bf(f); }
__device__ __forceinline__ ushort to_bf(ushort u) { return u; }

#define NPIX 16384  // H*W = 128*128

// ---------------------------------------------------------------------------
// K0: convert fp32 weights to bf16 once (qkv_w, pin_w, pout_w).
// ---------------------------------------------------------------------------
__global__ __launch_bounds__(256) void wcvt(const float* __restrict__ s0, ushort* __restrict__ d0, int n0,
                                            const float* __restrict__ s1, ushort* __restrict__ d1, int n1,
                                            const float* __restrict__ s2, ushort* __restrict__ d2, int n2) {
    int i = blockIdx.x * 256 + threadIdx.x;
    if (i < n0) d0[i] = f2bf(s0[i]);
    else if (i < n0 + n1) d1[i - n0] = f2bf(s1[i - n0]);
    else if (i < n0 + n1 + n2) d2[i - n0 - n1] = f2bf(s2[i - n0 - n1]);
}

// ---------------------------------------------------------------------------
// K1/K5: fused LayerNorm(C=128) + 1x1 conv via MFMA.
// Block = 64 px, 4 waves. LDS xs[64][136] bf16 (transposed, padded).
// Wave w owns M-range of O; all 4 n-groups (16 px each) in registers.
// ---------------------------------------------------------------------------
template <int O, typename TIN>
__global__ __launch_bounds__(256) void ln_gemm_mfma(const TIN* __restrict__ xin,
                                                    const ushort* __restrict__ Wb,
                                                    const float* __restrict__ gamma,
                                                    const float* __restrict__ beta,
                                                    ushort* __restrict__ out) {
    __shared__ ushort xs[64][136];
    __shared__ float red[2][4][64];
    __shared__ float mu[64], rs[64];
    __shared__ float gl[128], bl[128];

    const int blk = blockIdx.x;
    const int b = blk >> 8;
    const int pix0 = (blk & 255) * 64;
    const int tid = threadIdx.x;

    // stage x tile -> LDS transposed [p][c], bf16
    const TIN* xb = xin + (size_t)b * 128 * NPIX + pix0;
    for (int i = tid; i < 1024; i += 256) {
        int p = i & 63, cg = i >> 6;
        const TIN* src = xb + (size_t)(cg * 8) * NPIX + p;
        ushort8v u;
#pragma unroll
        for (int j = 0; j < 8; j++) u[j] = to_bf(src[(size_t)j * NPIX]);
        *(ushort8v*)&xs[p][cg * 8] = u;
    }
    if (tid < 128) {
        gl[tid] = gamma[tid];
        bl[tid] = beta[tid];
    }
    __syncthreads();

    // per-pixel LN stats (4 threads per pixel)
    {
        const int p = tid & 63, part = tid >> 6;
        float s = 0.f, ss = 0.f;
#pragma unroll
        for (int q = 0; q < 4; q++) {
            ushort8v u = *(const ushort8v*)&xs[p][part * 32 + q * 8];
#pragma unroll
            for (int j = 0; j < 8; j++) {
                float v = b2f(u[j]);
                s += v;
                ss += v * v;
            }
        }
        red[0][part][p] = s;
        red[1][part][p] = ss;
    }
    __syncthreads();
    if (tid < 64) {
        float s = red[0][0][tid] + red[0][1][tid] + red[0][2][tid] + red[0][3][tid];
        float ss = red[1][0][tid] + red[1][1][tid] + red[1][2][tid] + red[1][3][tid];
        float m = s * (1.f / 128.f);
        float var = ss * (1.f / 128.f) - m * m;
        mu[tid] = m;
        rs[tid] = rsqrtf(var + 1e-5f);
    }
    __syncthreads();
    // apply LN in place
    {
        const int p = tid & 63, part = tid >> 6;
        const float mp = mu[p], rp = rs[p];
#pragma unroll
        for (int q = 0; q < 4; q++) {
            int c0 = part * 32 + q * 8;
            ushort8v u = *(const ushort8v*)&xs[p][c0];
            ushort8v o;
#pragma unroll
            for (int j = 0; j < 8; j++) {
                float v = b2f(u[j]);
                o[j] = f2bf((v - mp) * rp * gl[c0 + j] + bl[c0 + j]);
            }
            *(ushort8v*)&xs[p][c0] = o;
        }
    }
    __syncthreads();

    const int wv = tid >> 6, lane = tid & 63;
    const int lr = lane & 15, lg = lane >> 4;

    // B fragments: all 4 n-groups x 4 k-chunks
    bf16x8 bfr[4][4];
#pragma unroll
    for (int t = 0; t < 4; t++)
#pragma unroll
        for (int kc = 0; kc < 4; kc++)
            bfr[t][kc] = __builtin_bit_cast(bf16x8, *(const ushort8v*)&xs[t * 16 + lr][kc * 32 + lg * 8]);

    constexpr int MT = O / 64;  // M tiles per wave
#pragma unroll 1
    for (int mt = 0; mt < MT; mt++) {
        const int o0 = (wv * MT + mt) * 16;
        bf16x8 afr[4];
#pragma unroll
        for (int kc = 0; kc < 4; kc++)
            afr[kc] = __builtin_bit_cast(bf16x8,
                *(const ushort8v*)&Wb[(size_t)(o0 + lr) * 128 + kc * 32 + lg * 8]);
        f32x4 acc[4] = {{0.f, 0.f, 0.f, 0.f}, {0.f, 0.f, 0.f, 0.f}, {0.f, 0.f, 0.f, 0.f}, {0.f, 0.f, 0.f, 0.f}};
#pragma unroll
        for (int kc = 0; kc < 4; kc++)
#pragma unroll
            for (int t = 0; t < 4; t++)
                acc[t] = __builtin_amdgcn_mfma_f32_16x16x32_bf16(afr[kc], bfr[t][kc], acc[t], 0, 0, 0);
#pragma unroll
        for (int t = 0; t < 4; t++)
#pragma unroll
            for (int r = 0; r < 4; r++) {
                int o = o0 + lg * 4 + r;
                out[((size_t)b * O + o) * NPIX + pix0 + t * 16 + lr] = f2bf(acc[t][r]);
            }
    }
}

// ---------------------------------------------------------------------------
// K2/K6/K7: depthwise conv, zero padding (unchanged this round).
// ---------------------------------------------------------------------------
template <int KS>
__global__ __launch_bounds__(256) void dwconv(const ushort* __restrict__ in,
                                              const float* __restrict__ wdw,
                                              ushort* __restrict__ out, int CH) {
    size_t idx = (size_t)blockIdx.x * 256 + threadIdx.x;
    int xw = idx & 127;
    int y = (idx >> 7) & 127;
    size_t bc = idx >> 14;
    int c = (int)(bc % CH);
    const ushort* base = in + (bc << 14);
    const int P = KS / 2;
    float acc = 0.f;
#pragma unroll
    for (int dy = -P; dy <= P; dy++) {
        int yy = y + dy;
        if (yy < 0 || yy > 127) continue;
#pragma unroll
        for (int dx = -P; dx <= P; dx++) {
            int xx = xw + dx;
            if (xx < 0 || xx > 127) continue;
            acc += b2f(base[yy * 128 + xx]) * wdw[c * KS * KS + (dy + P) * KS + (dx + P)];
        }
    }
    out[idx] = f2bf(acc);
}

// ---------------------------------------------------------------------------
// K3a: L2 norms of q and k rows (unchanged).
// ---------------------------------------------------------------------------
__global__ __launch_bounds__(256) void l2norms(const ushort* __restrict__ qkv,
                                               float* __restrict__ norms) {
    int blk = blockIdx.x;
    int qk = blk & 1, d = (blk >> 1) & 15, h = (blk >> 5) & 7, b = blk >> 8;
    int ch = qk * 128 + h * 16 + d;
    const ushort* row = qkv + ((size_t)b * 384 + ch) * NPIX;
    float s = 0.f;
    for (int i = threadIdx.x; i < NPIX; i += 256) {
        float v = b2f(row[i]);
        s += v * v;
    }
    for (int off = 32; off; off >>= 1) s += __shfl_down(s, off, 64);
    __shared__ float red[4];
    if ((threadIdx.x & 63) == 0) red[threadIdx.x >> 6] = s;
    __syncthreads();
    if (threadIdx.x == 0) {
        float t = red[0] + red[1] + red[2] + red[3];
        norms[blk] = fmaxf(sqrtf(t), 1e-12f);
    }
}

// ---------------------------------------------------------------------------
// K3b: partial q·k^T dot products (unchanged).
// ---------------------------------------------------------------------------
__global__ __launch_bounds__(256) void qk_partial(const ushort* __restrict__ qkv,
                                                  float* __restrict__ Spart) {
    __shared__ float qs[16][260], ks[16][260];
    int blk = blockIdx.x;
    int seg = blk & 3, h = (blk >> 2) & 7, b = blk >> 5;
    int bh = b * 8 + h;
    int n0 = seg * 4096;
    int tid = threadIdx.x;
    int d = tid >> 4, e = tid & 15;
    float acc = 0.f;
    for (int c0 = 0; c0 < 4096; c0 += 256) {
        __syncthreads();
        for (int i = tid; i < 16 * 256; i += 256) {
            int r = i >> 8, col = i & 255;
            qs[r][col] = b2f(qkv[((size_t)b * 384 + h * 16 + r) * NPIX + n0 + c0 + col]);
            ks[r][col] = b2f(qkv[((size_t)b * 384 + 128 + h * 16 + r) * NPIX + n0 + c0 + col]);
        }
        __syncthreads();
        for (int nn = 0; nn < 256; nn += 4) {
            float4 qv = *(const float4*)&qs[d][nn];
            float4 kv = *(const float4*)&ks[e][nn];
            acc += qv.x * kv.x + qv.y * kv.y + qv.z * kv.z + qv.w * kv.w;
        }
    }
    Spart[((size_t)seg * 64 + bh) * 256 + tid] = acc;
}

// ---------------------------------------------------------------------------
// K3c: softmax + fold attn into attn_proj -> M (bf16 now).
// ---------------------------------------------------------------------------
__global__ __launch_bounds__(256) void softmax_M(const float* __restrict__ Spart,
                                                 const float* __restrict__ norms,
                                                 const float* __restrict__ temp,
                                                 const float* __restrict__ attn_proj,
                                                 ushort* __restrict__ M) {
    int bh = blockIdx.x;
    int b = bh >> 3, h = bh & 7;
    int tid = threadIdx.x;
    int d = tid >> 4, e = tid & 15;
    float s = Spart[(0 * 64 + bh) * 256 + tid] + Spart[(1 * 64 + bh) * 256 + tid] +
              Spart[(2 * 64 + bh) * 256 + tid] + Spart[(3 * 64 + bh) * 256 + tid];
    float nq = norms[((b * 8 + h) * 16 + d) * 2 + 0];
    float nk = norms[((b * 8 + h) * 16 + e) * 2 + 1];
    float logit = s / (nq * nk) * temp[h];
    float m = logit;
    for (int off = 8; off; off >>= 1) m = fmaxf(m, __shfl_xor(m, off, 64));
    float ex = expf(logit - m);
    float sum = ex;
    for (int off = 8; off; off >>= 1) sum += __shfl_xor(sum, off, 64);
    float attn = ex / sum;
    __shared__ float A[16][17];
    A[d][e] = attn;
    __syncthreads();
    for (int i = tid; i < 128 * 16; i += 256) {
        int o = i >> 4, ee = i & 15;
        float acc = 0.f;
#pragma unroll
        for (int dd = 0; dd < 16; dd++) acc += attn_proj[o * 128 + h * 16 + dd] * A[dd][ee];
        M[((size_t)b * 128 + o) * 128 + h * 16 + ee] = f2bf(acc);
    }
}

// ---------------------------------------------------------------------------
// K4: x2 = x + M_b @ v via MFMA. Same skeleton as ln_gemm_mfma minus LN.
// ---------------------------------------------------------------------------
__global__ __launch_bounds__(256) void mv_res_mfma(const ushort* __restrict__ qkv,
                                                   const ushort* __restrict__ Mb16,
                                                   const float* __restrict__ x,
                                                   ushort* __restrict__ x2) {
    __shared__ ushort vs[64][136];
    const int blk = blockIdx.x;
    const int b = blk >> 8;
    const int pix0 = (blk & 255) * 64;
    const int tid = threadIdx.x;

    const ushort* vb = qkv + ((size_t)b * 384 + 256) * NPIX + pix0;
    for (int i = tid; i < 1024; i += 256) {
        int p = i & 63, cg = i >> 6;
        const ushort* src = vb + (size_t)(cg * 8) * NPIX + p;
        ushort8v u;
#pragma unroll
        for (int j = 0; j < 8; j++) u[j] = src[(size_t)j * NPIX];
        *(ushort8v*)&vs[p][cg * 8] = u;
    }
    __syncthreads();

    const int wv = tid >> 6, lane = tid & 63;
    const int lr = lane & 15, lg = lane >> 4;

    bf16x8 bfr[4][4];
#pragma unroll
    for (int t = 0; t < 4; t++)
#pragma unroll
        for (int kc = 0; kc < 4; kc++)
            bfr[t][kc] = __builtin_bit_cast(bf16x8, *(const ushort8v*)&vs[t * 16 + lr][kc * 32 + lg * 8]);

    const ushort* Mb = Mb16 + (size_t)b * 128 * 128;
#pragma unroll 1
    for (int mt = 0; mt < 2; mt++) {
        const int o0 = (wv * 2 + mt) * 16;
        bf16x8 afr[4];
#pragma unroll
        for (int kc = 0; kc < 4; kc++)
            afr[kc] = __builtin_bit_cast(bf16x8,
                *(const ushort8v*)&Mb[(size_t)(o0 + lr) * 128 + kc * 32 + lg * 8]);
        f32x4 acc[4] = {{0.f, 0.f, 0.f, 0.f}, {0.f, 0.f, 0.f, 0.f}, {0.f, 0.f, 0.f, 0.f}, {0.f, 0.f, 0.f, 0.f}};
#pragma unroll
        for (int kc = 0; kc < 4; kc++)
#pragma unroll
            for (int t = 0; t < 4; t++)
                acc[t] = __builtin_amdgcn_mfma_f32_16x16x32_bf16(afr[kc], bfr[t][kc], acc[t], 0, 0, 0);
#pragma unroll
        for (int t = 0; t < 4; t++)
#pragma unroll
            for (int r = 0; r < 4; r++) {
                int o = o0 + lg * 4 + r;
                size_t off = ((size_t)b * 128 + o) * NPIX + pix0 + t * 16 + lr;
                x2[off] = f2bf(x[off] + acc[t][r]);
            }
    }
}

// ---------------------------------------------------------------------------
// K8: out = x2 + pout[128,512] @ gated via MFMA; gated chunk built per 64-k.
// ---------------------------------------------------------------------------
__global__ __launch_bounds__(256) void gdfn_mfma(const ushort* __restrict__ t,
                                                 const ushort* __restrict__ x3,
                                                 const ushort* __restrict__ x5,
                                                 const ushort* __restrict__ x2,
                                                 const float* __restrict__ c1w,
                                                 const ushort* __restrict__ pout_b,
                                                 float* __restrict__ out) {
    __shared__ ushort gs[64][72];  // [px][k-chunk 64 + pad]

    const int blk = blockIdx.x;
    const int b = blk >> 8;
    const int pix0 = (blk & 255) * 64;
    const int tid = threadIdx.x;
    const int wv = tid >> 6, lane = tid & 63;
    const int lr = lane & 15, lg = lane >> 4;

    f32x4 acc[2][4];
#pragma unroll
    for (int mt = 0; mt < 2; mt++)
#pragma unroll
        for (int tt = 0; tt < 4; tt++) acc[mt][tt] = (f32x4){0.f, 0.f, 0.f, 0.f};

#pragma unroll 1
    for (int kb = 0; kb < 8; kb++) {
        const ushort* xg = (kb < 4) ? x3 : x5;
        const int cbase = (kb & 3) * 64;
        __syncthreads();  // previous chunk's ds_reads complete
        for (int i = tid; i < 512; i += 256) {
            int p = i & 63, kg = i >> 6;
            ushort8v u;
#pragma unroll
            for (int j = 0; j < 8; j++) {
                int ch = cbase + kg * 8 + j;
                size_t off = ((size_t)b * 256 + ch) * NPIX + pix0 + p;
                float x1 = b2f(t[off]) * c1w[ch];
                float g = 0.5f * x1 * (1.f + erff(x1 * 0.70710678118f));
                u[j] = f2bf(g * b2f(xg[off]));
            }
            *(ushort8v*)&gs[p][kg * 8] = u;
        }
        __syncthreads();

        bf16x8 bfrg[4][2];
#pragma unroll
        for (int tt = 0; tt < 4; tt++)
#pragma unroll
            for (int kc = 0; kc < 2; kc++)
                bfrg[tt][kc] = __builtin_bit_cast(bf16x8, *(const ushort8v*)&gs[tt * 16 + lr][kc * 32 + lg * 8]);

#pragma unroll
        for (int mt = 0; mt < 2; mt++) {
            const int o0 = (wv * 2 + mt) * 16;
            bf16x8 afr[2];
#pragma unroll
            for (int kc = 0; kc < 2; kc++)
                afr[kc] = __builtin_bit_cast(bf16x8,
                    *(const ushort8v*)&pout_b[(size_t)(o0 + lr) * 512 + kb * 64 + kc * 32 + lg * 8]);
#pragma unroll
            for (int kc = 0; kc < 2; kc++)
#pragma unroll
                for (int tt = 0; tt < 4; tt++)
                    acc[mt][tt] = __builtin_amdgcn_mfma_f32_16x16x32_bf16(afr[kc], bfrg[tt][kc], acc[mt][tt], 0, 0, 0);
        }
    }

#pragma unroll
    for (int mt = 0; mt < 2; mt++)
#pragma unroll
        for (int tt = 0; tt < 4; tt++)
#pragma unroll
            for (int r = 0; r < 4; r++) {
                int o = (wv * 2 + mt) * 16 + lg * 4 + r;
                size_t off = ((size_t)b * 128 + o) * NPIX + pix0 + tt * 16 + lr;
                out[off] = b2f(x2[off]) + acc[mt][tt][r];
            }
}

// ---------------------------------------------------------------------------
extern "C" void kernel_launch(void* const* d_in, const int* in_sizes, int n_in,
                              void* d_out, int out_size, void* d_ws, size_t ws_size,
                              hipStream_t stream) {
    const float* x = (const float*)d_in[0];
    const float* ln1_w = (const float*)d_in[1];
    const float* ln1_b = (const float*)d_in[2];
    const float* qkv_w = (const float*)d_in[3];
    const float* qkv_dw = (const float*)d_in[4];
    const float* temperature = (const float*)d_in[5];
    const float* attn_proj = (const float*)d_in[6];
    const float* ln2_w = (const float*)d_in[7];
    const float* ln2_b = (const float*)d_in[8];
    const float* pin_w = (const float*)d_in[9];
    const float* c1_w = (const float*)d_in[10];
    const float* c3_w = (const float*)d_in[11];
    const float* c5_w = (const float*)d_in[12];
    const float* pout_w = (const float*)d_in[13];
    float* out = (float*)d_out;

    char* ws = (char*)d_ws;
    ushort* qkv_pre = (ushort*)(ws + 0);            // 100,663,296 (dead after K2)
    ushort* qkv     = (ushort*)(ws + 100663296);    // 100,663,296 (dead after K4)
    ushort* x2      = (ushort*)(ws + 201326592);    //  33,554,432 (lives to end)
    ushort* t       = (ushort*)(ws + 0);            //  67,108,864 (reuses qkv_pre)
    ushort* x3      = (ushort*)(ws + 67108864);     //  67,108,864
    ushort* x5      = (ushort*)(ws + 134217728);    //  67,108,864
    float*  norms   = (float*)(ws + 234881024);     //      8,192
    float*  Spart   = (float*)(ws + 234889216);     //    262,144
    ushort* Mb16    = (ushort*)(ws + 235151360);    //    262,144
    ushort* qkv_wb  = (ushort*)(ws + 235413504);    //     98,304
    ushort* pin_wb  = (ushort*)(ws + 235511808);    //     65,536
    ushort* pout_wb = (ushort*)(ws + 235577344);    //    131,072  (end ~235.7 MB)

    // K0: weight conversion (f32 -> bf16)
    wcvt<<<576, 256, 0, stream>>>(qkv_w, qkv_wb, 49152, pin_w, pin_wb, 32768, pout_w, pout_wb, 65536);
    // K1: qkv_pre = qkv_w @ LN1(x)
    ln_gemm_mfma<384, float><<<2048, 256, 0, stream>>>(x, qkv_wb, ln1_w, ln1_b, qkv_pre);
    // K2: qkv = dwconv3x3(qkv_pre)
    dwconv<3><<<196608, 256, 0, stream>>>(qkv_pre, qkv_dw, qkv, 384);
    // K3: tiny attention folded into per-batch projection matrix M
    l2norms<<<2048, 256, 0, stream>>>(qkv, norms);
    qk_partial<<<256, 256, 0, stream>>>(qkv, Spart);
    softmax_M<<<64, 256, 0, stream>>>(Spart, norms, temperature, attn_proj, Mb16);
    // K4: x2 = x + M_b @ v
    mv_res_mfma<<<2048, 256, 0, stream>>>(qkv, Mb16, x, x2);
    // K5: t = pin_w @ LN2(x2)
    ln_gemm_mfma<256, ushort><<<2048, 256, 0, stream>>>(x2, pin_wb, ln2_w, ln2_b, t);
    // K6/K7: x3 = dw3x3(t), x5 = dw5x5(t)
    dwconv<3><<<131072, 256, 0, stream>>>(t, c3_w, x3, 256);
    dwconv<5><<<131072, 256, 0, stream>>>(t, c5_w, x5, 256);
    // K8: out = x2 + pout @ [gelu(t*c1)*x3 ; gelu(t*c1)*x5]
    gdfn_mfma<<<2048, 256, 0, stream>>>(t, x3, x5, x2, c1_w, pout_wb, out);
}

// Round 5
// 403.943 us; speedup vs baseline: 55.1881x; 3.0144x over previous
//
#include <hip/hip_runtime.h>

typedef unsigned short ushort;
typedef unsigned int uint;
typedef __bf16 bf16x8 __attribute__((ext_vector_type(8)));
typedef unsigned short ushort8v __attribute__((ext_vector_type(8)));
typedef float f32x4 __attribute__((ext_vector_type(4)));

__device__ __forceinline__ float b2f(ushort u) {
    unsigned int x = ((unsigned int)u) << 16;
    float f;
    __builtin_memcpy(&f, &x, 4);
    return f;
}
__device__ __forceinline__ ushort f2bf(float f) {
    unsigned int x;
    __builtin_memcpy(&x, &f, 4);
    unsigned int r = x + 0x7fffu + ((x >> 16) & 1u);
    return (ushort)(r >> 16);
}
__device__ __forceinline__ float u2f_lo(uint u) {
    uint x = u << 16;
    float f;
    __builtin_memcpy(&f, &x, 4);
    return f;
}
__device__ __forceinline__ float u2f_hi(uint u) {
    uint x = u & 0xffff0000u;
    float f;
    __builtin_memcpy(&f, &x, 4);
    return f;
}
__device__ __forceinline__ uint packbf(float a, float b) {
    return (uint)f2bf(a) | ((uint)f2bf(b) << 16);
}
__device__ __forceinline__ ushort to_bf(float f) { return f2bf(f); }
__device__ __forceinline__ ushort to_bf(ushort u) { return u; }

#define NPIX 16384  // H*W = 128*128
#define PSTRIDE 136 // padded plane row stride (ushorts)

// ---------------------------------------------------------------------------
// shared helper: zero-fill + stage one 128x128 bf16 plane into padded LDS
// pl is ushort[132*136], interior at [y+2][x+2].
// ---------------------------------------------------------------------------
__device__ __forceinline__ void stage_plane(ushort* pl, const ushort* __restrict__ src, int tid) {
    for (int i = tid; i < 132 * PSTRIDE / 2; i += 256) ((uint*)pl)[i] = 0u;
    __syncthreads();
    for (int i = tid; i < 2048; i += 256) {
        int row = i >> 4, xg = (i & 15) << 3;
        uint4 v = *(const uint4*)&src[row * 128 + xg];
        uint* dst = (uint*)&pl[(row + 2) * PSTRIDE + xg + 2];
        dst[0] = v.x; dst[1] = v.y; dst[2] = v.z; dst[3] = v.w;
    }
    __syncthreads();
}

// ---------------------------------------------------------------------------
// K0: convert fp32 weights to bf16 once (qkv_w, pin_w, pout_w).
// ---------------------------------------------------------------------------
__global__ __launch_bounds__(256) void wcvt(const float* __restrict__ s0, ushort* __restrict__ d0, int n0,
                                            const float* __restrict__ s1, ushort* __restrict__ d1, int n1,
                                            const float* __restrict__ s2, ushort* __restrict__ d2, int n2) {
    int i = blockIdx.x * 256 + threadIdx.x;
    if (i < n0) d0[i] = f2bf(s0[i]);
    else if (i < n0 + n1) d1[i - n0] = f2bf(s1[i - n0]);
    else if (i < n0 + n1 + n2) d2[i - n0 - n1] = f2bf(s2[i - n0 - n1]);
}

// ---------------------------------------------------------------------------
// K1/K5: fused LayerNorm(C=128) + 1x1 conv via MFMA (unchanged from R4).
// ---------------------------------------------------------------------------
template <int O, typename TIN>
__global__ __launch_bounds__(256) void ln_gemm_mfma(const TIN* __restrict__ xin,
                                                    const ushort* __restrict__ Wb,
                                                    const float* __restrict__ gamma,
                                                    const float* __restrict__ beta,
                                                    ushort* __restrict__ out) {
    __shared__ ushort xs[64][136];
    __shared__ float red[2][4][64];
    __shared__ float mu[64], rs[64];
    __shared__ float gl[128], bl[128];

    const int blk = blockIdx.x;
    const int b = blk >> 8;
    const int pix0 = (blk & 255) * 64;
    const int tid = threadIdx.x;

    const TIN* xb = xin + (size_t)b * 128 * NPIX + pix0;
    for (int i = tid; i < 1024; i += 256) {
        int p = i & 63, cg = i >> 6;
        const TIN* src = xb + (size_t)(cg * 8) * NPIX + p;
        ushort8v u;
#pragma unroll
        for (int j = 0; j < 8; j++) u[j] = to_bf(src[(size_t)j * NPIX]);
        *(ushort8v*)&xs[p][cg * 8] = u;
    }
    if (tid < 128) {
        gl[tid] = gamma[tid];
        bl[tid] = beta[tid];
    }
    __syncthreads();

    {
        const int p = tid & 63, part = tid >> 6;
        float s = 0.f, ss = 0.f;
#pragma unroll
        for (int q = 0; q < 4; q++) {
            ushort8v u = *(const ushort8v*)&xs[p][part * 32 + q * 8];
#pragma unroll
            for (int j = 0; j < 8; j++) {
                float v = b2f(u[j]);
                s += v;
                ss += v * v;
            }
        }
        red[0][part][p] = s;
        red[1][part][p] = ss;
    }
    __syncthreads();
    if (tid < 64) {
        float s = red[0][0][tid] + red[0][1][tid] + red[0][2][tid] + red[0][3][tid];
        float ss = red[1][0][tid] + red[1][1][tid] + red[1][2][tid] + red[1][3][tid];
        float m = s * (1.f / 128.f);
        float var = ss * (1.f / 128.f) - m * m;
        mu[tid] = m;
        rs[tid] = rsqrtf(var + 1e-5f);
    }
    __syncthreads();
    {
        const int p = tid & 63, part = tid >> 6;
        const float mp = mu[p], rp = rs[p];
#pragma unroll
        for (int q = 0; q < 4; q++) {
            int c0 = part * 32 + q * 8;
            ushort8v u = *(const ushort8v*)&xs[p][c0];
            ushort8v o;
#pragma unroll
            for (int j = 0; j < 8; j++) {
                float v = b2f(u[j]);
                o[j] = f2bf((v - mp) * rp * gl[c0 + j] + bl[c0 + j]);
            }
            *(ushort8v*)&xs[p][c0] = o;
        }
    }
    __syncthreads();

    const int wv = tid >> 6, lane = tid & 63;
    const int lr = lane & 15, lg = lane >> 4;

    bf16x8 bfr[4][4];
#pragma unroll
    for (int t = 0; t < 4; t++)
#pragma unroll
        for (int kc = 0; kc < 4; kc++)
            bfr[t][kc] = __builtin_bit_cast(bf16x8, *(const ushort8v*)&xs[t * 16 + lr][kc * 32 + lg * 8]);

    constexpr int MT = O / 64;
#pragma unroll 1
    for (int mt = 0; mt < MT; mt++) {
        const int o0 = (wv * MT + mt) * 16;
        bf16x8 afr[4];
#pragma unroll
        for (int kc = 0; kc < 4; kc++)
            afr[kc] = __builtin_bit_cast(bf16x8,
                *(const ushort8v*)&Wb[(size_t)(o0 + lr) * 128 + kc * 32 + lg * 8]);
        f32x4 acc[4] = {{0.f, 0.f, 0.f, 0.f}, {0.f, 0.f, 0.f, 0.f}, {0.f, 0.f, 0.f, 0.f}, {0.f, 0.f, 0.f, 0.f}};
#pragma unroll
        for (int kc = 0; kc < 4; kc++)
#pragma unroll
            for (int t = 0; t < 4; t++)
                acc[t] = __builtin_amdgcn_mfma_f32_16x16x32_bf16(afr[kc], bfr[t][kc], acc[t], 0, 0, 0);
#pragma unroll
        for (int t = 0; t < 4; t++)
#pragma unroll
            for (int r = 0; r < 4; r++) {
                int o = o0 + lg * 4 + r;
                out[((size_t)b * O + o) * NPIX + pix0 + t * 16 + lr] = f2bf(acc[t][r]);
            }
    }
}

// ---------------------------------------------------------------------------
// K2 (NEW): 3x3 depthwise conv, one (b,c) plane per block in padded LDS.
// grid = (CH, B). Branch-free taps; each thread does 32 px-pairs.
// ---------------------------------------------------------------------------
__global__ __launch_bounds__(256) void dwconv3_lds(const ushort* __restrict__ in,
                                                   const float* __restrict__ wdw,
                                                   ushort* __restrict__ out) {
    __shared__ ushort pl[132 * PSTRIDE];
    const int c = blockIdx.x;
    const size_t plane = ((size_t)blockIdx.y * gridDim.x + c) * NPIX;
    const int tid = threadIdx.x;

    float w[9];
#pragma unroll
    for (int j = 0; j < 9; j++) w[j] = wdw[c * 9 + j];

    stage_plane(pl, in + plane, tid);

    for (int k = 0; k < 32; k++) {
        int idx = tid + k * 256;
        int px0 = idx * 2;
        int x = px0 & 127, y = px0 >> 7;
        float a0 = 0.f, a1 = 0.f;
#pragma unroll
        for (int ky = 0; ky < 3; ky++) {
            const uint* rp = (const uint*)&pl[(y + ky + 1) * PSTRIDE + x];
            uint u0 = rp[0], u1 = rp[1], u2 = rp[2];
            float c1 = u2f_hi(u0), c2 = u2f_lo(u1), c3 = u2f_hi(u1), c4 = u2f_lo(u2);
            a0 += c1 * w[ky * 3] + c2 * w[ky * 3 + 1] + c3 * w[ky * 3 + 2];
            a1 += c2 * w[ky * 3] + c3 * w[ky * 3 + 1] + c4 * w[ky * 3 + 2];
        }
        *(uint*)&out[plane + px0] = packbf(a0, a1);
    }
}

// ---------------------------------------------------------------------------
// K6/K7/gating (NEW, fused): per (b,c) plane of t, compute
//   x3 = dw3x3(t), x5 = dw5x5(t), g = gelu(t*c1), write g*x3 and g*x5
// into gated[b][c][*] and gated[b][256+c][*].  grid = (256, B).
// 3x3 window is a subset of the 5x5 loaded columns -> zero extra LDS reads.
// ---------------------------------------------------------------------------
__global__ __launch_bounds__(256) void dw_gated(const ushort* __restrict__ t,
                                                const float* __restrict__ w3_,
                                                const float* __restrict__ w5_,
                                                const float* __restrict__ c1w,
                                                ushort* __restrict__ gated) {
    __shared__ ushort pl[132 * PSTRIDE];
    const int c = blockIdx.x;
    const int b = blockIdx.y;
    const int tid = threadIdx.x;

    float w3[9], w5[25];
#pragma unroll
    for (int j = 0; j < 9; j++) w3[j] = w3_[c * 9 + j];
#pragma unroll
    for (int j = 0; j < 25; j++) w5[j] = w5_[c * 25 + j];
    const float c1v = c1w[c];

    stage_plane(pl, t + ((size_t)b * 256 + c) * NPIX, tid);

    ushort* g3 = gated + ((size_t)b * 512 + c) * NPIX;
    ushort* g5 = g3 + (size_t)256 * NPIX;

    for (int k = 0; k < 32; k++) {
        int idx = tid + k * 256;
        int px0 = idx * 2;
        int x = px0 & 127, y = px0 >> 7;
        float a5_0 = 0.f, a5_1 = 0.f, a3_0 = 0.f, a3_1 = 0.f;
        float t0 = 0.f, t1 = 0.f;
#pragma unroll
        for (int ky = 0; ky < 5; ky++) {
            const uint* rp = (const uint*)&pl[(y + ky) * PSTRIDE + x];
            uint u0 = rp[0], u1 = rp[1], u2 = rp[2];
            float cc[6] = {u2f_lo(u0), u2f_hi(u0), u2f_lo(u1), u2f_hi(u1), u2f_lo(u2), u2f_hi(u2)};
#pragma unroll
            for (int kx = 0; kx < 5; kx++) {
                a5_0 += cc[kx] * w5[ky * 5 + kx];
                a5_1 += cc[kx + 1] * w5[ky * 5 + kx];
            }
            if (ky >= 1 && ky <= 3) {
#pragma unroll
                for (int kx = 0; kx < 3; kx++) {
                    a3_0 += cc[kx + 1] * w3[(ky - 1) * 3 + kx];
                    a3_1 += cc[kx + 2] * w3[(ky - 1) * 3 + kx];
                }
            }
            if (ky == 2) { t0 = cc[2]; t1 = cc[3]; }
        }
        float x1a = t0 * c1v, x1b = t1 * c1v;
        float g0 = 0.5f * x1a * (1.f + erff(x1a * 0.70710678118f));
        float g1 = 0.5f * x1b * (1.f + erff(x1b * 0.70710678118f));
        *(uint*)&g3[px0] = packbf(g0 * a3_0, g1 * a3_1);
        *(uint*)&g5[px0] = packbf(g0 * a5_0, g1 * a5_1);
    }
}

// ---------------------------------------------------------------------------
// K3a: L2 norms of q and k rows (unchanged).
// ---------------------------------------------------------------------------
__global__ __launch_bounds__(256) void l2norms(const ushort* __restrict__ qkv,
                                               float* __restrict__ norms) {
    int blk = blockIdx.x;
    int qk = blk & 1, d = (blk >> 1) & 15, h = (blk >> 5) & 7, b = blk >> 8;
    int ch = qk * 128 + h * 16 + d;
    const ushort* row = qkv + ((size_t)b * 384 + ch) * NPIX;
    float s = 0.f;
    for (int i = threadIdx.x; i < NPIX; i += 256) {
        float v = b2f(row[i]);
        s += v * v;
    }
    for (int off = 32; off; off >>= 1) s += __shfl_down(s, off, 64);
    __shared__ float red[4];
    if ((threadIdx.x & 63) == 0) red[threadIdx.x >> 6] = s;
    __syncthreads();
    if (threadIdx.x == 0) {
        float t = red[0] + red[1] + red[2] + red[3];
        norms[blk] = fmaxf(sqrtf(t), 1e-12f);
    }
}

// ---------------------------------------------------------------------------
// K3b: partial q·k^T dot products (unchanged).
// ---------------------------------------------------------------------------
__global__ __launch_bounds__(256) void qk_partial(const ushort* __restrict__ qkv,
                                                  float* __restrict__ Spart) {
    __shared__ float qs[16][260], ks[16][260];
    int blk = blockIdx.x;
    int seg = blk & 3, h = (blk >> 2) & 7, b = blk >> 5;
    int bh = b * 8 + h;
    int n0 = seg * 4096;
    int tid = threadIdx.x;
    int d = tid >> 4, e = tid & 15;
    float acc = 0.f;
    for (int c0 = 0; c0 < 4096; c0 += 256) {
        __syncthreads();
        for (int i = tid; i < 16 * 256; i += 256) {
            int r = i >> 8, col = i & 255;
            qs[r][col] = b2f(qkv[((size_t)b * 384 + h * 16 + r) * NPIX + n0 + c0 + col]);
            ks[r][col] = b2f(qkv[((size_t)b * 384 + 128 + h * 16 + r) * NPIX + n0 + c0 + col]);
        }
        __syncthreads();
        for (int nn = 0; nn < 256; nn += 4) {
            float4 qv = *(const float4*)&qs[d][nn];
            float4 kv = *(const float4*)&ks[e][nn];
            acc += qv.x * kv.x + qv.y * kv.y + qv.z * kv.z + qv.w * kv.w;
        }
    }
    Spart[((size_t)seg * 64 + bh) * 256 + tid] = acc;
}

// ---------------------------------------------------------------------------
// K3c: softmax + fold attn into attn_proj -> M bf16 (unchanged).
// ---------------------------------------------------------------------------
__global__ __launch_bounds__(256) void softmax_M(const float* __restrict__ Spart,
                                                 const float* __restrict__ norms,
                                                 const float* __restrict__ temp,
                                                 const float* __restrict__ attn_proj,
                                                 ushort* __restrict__ M) {
    int bh = blockIdx.x;
    int b = bh >> 3, h = bh & 7;
    int tid = threadIdx.x;
    int d = tid >> 4, e = tid & 15;
    float s = Spart[(0 * 64 + bh) * 256 + tid] + Spart[(1 * 64 + bh) * 256 + tid] +
              Spart[(2 * 64 + bh) * 256 + tid] + Spart[(3 * 64 + bh) * 256 + tid];
    float nq = norms[((b * 8 + h) * 16 + d) * 2 + 0];
    float nk = norms[((b * 8 + h) * 16 + e) * 2 + 1];
    float logit = s / (nq * nk) * temp[h];
    float m = logit;
    for (int off = 8; off; off >>= 1) m = fmaxf(m, __shfl_xor(m, off, 64));
    float ex = expf(logit - m);
    float sum = ex;
    for (int off = 8; off; off >>= 1) sum += __shfl_xor(sum, off, 64);
    float attn = ex / sum;
    __shared__ float A[16][17];
    A[d][e] = attn;
    __syncthreads();
    for (int i = tid; i < 128 * 16; i += 256) {
        int o = i >> 4, ee = i & 15;
        float acc = 0.f;
#pragma unroll
        for (int dd = 0; dd < 16; dd++) acc += attn_proj[o * 128 + h * 16 + dd] * A[dd][ee];
        M[((size_t)b * 128 + o) * 128 + h * 16 + ee] = f2bf(acc);
    }
}

// ---------------------------------------------------------------------------
// K4: x2 = x + M_b @ v via MFMA (unchanged).
// ---------------------------------------------------------------------------
__global__ __launch_bounds__(256) void mv_res_mfma(const ushort* __restrict__ qkv,
                                                   const ushort* __restrict__ Mb16,
                                                   const float* __restrict__ x,
                                                   ushort* __restrict__ x2) {
    __shared__ ushort vs[64][136];
    const int blk = blockIdx.x;
    const int b = blk >> 8;
    const int pix0 = (blk & 255) * 64;
    const int tid = threadIdx.x;

    const ushort* vb = qkv + ((size_t)b * 384 + 256) * NPIX + pix0;
    for (int i = tid; i < 1024; i += 256) {
        int p = i & 63, cg = i >> 6;
        const ushort* src = vb + (size_t)(cg * 8) * NPIX + p;
        ushort8v u;
#pragma unroll
        for (int j = 0; j < 8; j++) u[j] = src[(size_t)j * NPIX];
        *(ushort8v*)&vs[p][cg * 8] = u;
    }
    __syncthreads();

    const int wv = tid >> 6, lane = tid & 63;
    const int lr = lane & 15, lg = lane >> 4;

    bf16x8 bfr[4][4];
#pragma unroll
    for (int t = 0; t < 4; t++)
#pragma unroll
        for (int kc = 0; kc < 4; kc++)
            bfr[t][kc] = __builtin_bit_cast(bf16x8, *(const ushort8v*)&vs[t * 16 + lr][kc * 32 + lg * 8]);

    const ushort* Mb = Mb16 + (size_t)b * 128 * 128;
#pragma unroll 1
    for (int mt = 0; mt < 2; mt++) {
        const int o0 = (wv * 2 + mt) * 16;
        bf16x8 afr[4];
#pragma unroll
        for (int kc = 0; kc < 4; kc++)
            afr[kc] = __builtin_bit_cast(bf16x8,
                *(const ushort8v*)&Mb[(size_t)(o0 + lr) * 128 + kc * 32 + lg * 8]);
        f32x4 acc[4] = {{0.f, 0.f, 0.f, 0.f}, {0.f, 0.f, 0.f, 0.f}, {0.f, 0.f, 0.f, 0.f}, {0.f, 0.f, 0.f, 0.f}};
#pragma unroll
        for (int kc = 0; kc < 4; kc++)
#pragma unroll
            for (int t = 0; t < 4; t++)
                acc[t] = __builtin_amdgcn_mfma_f32_16x16x32_bf16(afr[kc], bfr[t][kc], acc[t], 0, 0, 0);
#pragma unroll
        for (int t = 0; t < 4; t++)
#pragma unroll
            for (int r = 0; r < 4; r++) {
                int o = o0 + lg * 4 + r;
                size_t off = ((size_t)b * 128 + o) * NPIX + pix0 + t * 16 + lr;
                x2[off] = f2bf(x[off] + acc[t][r]);
            }
    }
}

// ---------------------------------------------------------------------------
// K8: out = x2 + pout[128,512] @ gated via MFMA. Pure GEMM now.
// ---------------------------------------------------------------------------
__global__ __launch_bounds__(256) void gdfn_mfma(const ushort* __restrict__ gated,
                                                 const ushort* __restrict__ x2,
                                                 const ushort* __restrict__ pout_b,
                                                 float* __restrict__ out) {
    __shared__ ushort gs[64][72];

    const int blk = blockIdx.x;
    const int b = blk >> 8;
    const int pix0 = (blk & 255) * 64;
    const int tid = threadIdx.x;
    const int wv = tid >> 6, lane = tid & 63;
    const int lr = lane & 15, lg = lane >> 4;

    f32x4 acc[2][4];
#pragma unroll
    for (int mt = 0; mt < 2; mt++)
#pragma unroll
        for (int tt = 0; tt < 4; tt++) acc[mt][tt] = (f32x4){0.f, 0.f, 0.f, 0.f};

#pragma unroll 1
    for (int kb = 0; kb < 8; kb++) {
        __syncthreads();
        for (int i = tid; i < 512; i += 256) {
            int p = i & 63, kg = i >> 6;
            const ushort* src = gated + ((size_t)b * 512 + kb * 64 + kg * 8) * NPIX + pix0 + p;
            ushort8v u;
#pragma unroll
            for (int j = 0; j < 8; j++) u[j] = src[(size_t)j * NPIX];
            *(ushort8v*)&gs[p][kg * 8] = u;
        }
        __syncthreads();

        bf16x8 bfrg[4][2];
#pragma unroll
        for (int tt = 0; tt < 4; tt++)
#pragma unroll
            for (int kc = 0; kc < 2; kc++)
                bfrg[tt][kc] = __builtin_bit_cast(bf16x8, *(const ushort8v*)&gs[tt * 16 + lr][kc * 32 + lg * 8]);

#pragma unroll
        for (int mt = 0; mt < 2; mt++) {
            const int o0 = (wv * 2 + mt) * 16;
            bf16x8 afr[2];
#pragma unroll
            for (int kc = 0; kc < 2; kc++)
                afr[kc] = __builtin_bit_cast(bf16x8,
                    *(const ushort8v*)&pout_b[(size_t)(o0 + lr) * 512 + kb * 64 + kc * 32 + lg * 8]);
#pragma unroll
            for (int kc = 0; kc < 2; kc++)
#pragma unroll
                for (int tt = 0; tt < 4; tt++)
                    acc[mt][tt] = __builtin_amdgcn_mfma_f32_16x16x32_bf16(afr[kc], bfrg[tt][kc], acc[mt][tt], 0, 0, 0);
        }
    }

#pragma unroll
    for (int mt = 0; mt < 2; mt++)
#pragma unroll
        for (int tt = 0; tt < 4; tt++)
#pragma unroll
            for (int r = 0; r < 4; r++) {
                int o = (wv * 2 + mt) * 16 + lg * 4 + r;
                size_t off = ((size_t)b * 128 + o) * NPIX + pix0 + tt * 16 + lr;
                out[off] = b2f(x2[off]) + acc[mt][tt][r];
            }
}

// ---------------------------------------------------------------------------
extern "C" void kernel_launch(void* const* d_in, const int* in_sizes, int n_in,
                              void* d_out, int out_size, void* d_ws, size_t ws_size,
                              hipStream_t stream) {
    const float* x = (const float*)d_in[0];
    const float* ln1_w = (const float*)d_in[1];
    const float* ln1_b = (const float*)d_in[2];
    const float* qkv_w = (const float*)d_in[3];
    const float* qkv_dw = (const float*)d_in[4];
    const float* temperature = (const float*)d_in[5];
    const float* attn_proj = (const float*)d_in[6];
    const float* ln2_w = (const float*)d_in[7];
    const float* ln2_b = (const float*)d_in[8];
    const float* pin_w = (const float*)d_in[9];
    const float* c1_w = (const float*)d_in[10];
    const float* c3_w = (const float*)d_in[11];
    const float* c5_w = (const float*)d_in[12];
    const float* pout_w = (const float*)d_in[13];
    float* out = (float*)d_out;

    char* ws = (char*)d_ws;
    ushort* qkv_pre = (ushort*)(ws + 0);            // 100,663,296 (dead after dwconv3)
    ushort* qkv     = (ushort*)(ws + 100663296);    // 100,663,296 (dead after mv_res)
    ushort* x2      = (ushort*)(ws + 201326592);    //  33,554,432 (lives to end)
    ushort* t       = (ushort*)(ws + 0);            //  67,108,864 (reuses qkv_pre)
    ushort* gated   = (ushort*)(ws + 67108864);     // 134,217,728 (reuses qkv region)
    float*  norms   = (float*)(ws + 234881024);     //      8,192
    float*  Spart   = (float*)(ws + 234889216);     //    262,144
    ushort* Mb16    = (ushort*)(ws + 235151360);    //    262,144
    ushort* qkv_wb  = (ushort*)(ws + 235413504);    //     98,304
    ushort* pin_wb  = (ushort*)(ws + 235511808);    //     65,536
    ushort* pout_wb = (ushort*)(ws + 235577344);    //    131,072  (end ~235.7 MB)

    // K0: weight conversion (f32 -> bf16)
    wcvt<<<576, 256, 0, stream>>>(qkv_w, qkv_wb, 49152, pin_w, pin_wb, 32768, pout_w, pout_wb, 65536);
    // K1: qkv_pre = qkv_w @ LN1(x)
    ln_gemm_mfma<384, float><<<2048, 256, 0, stream>>>(x, qkv_wb, ln1_w, ln1_b, qkv_pre);
    // K2: qkv = dwconv3x3(qkv_pre), plane-per-block LDS
    dwconv3_lds<<<dim3(384, 8), 256, 0, stream>>>(qkv_pre, qkv_dw, qkv);
    // K3: tiny attention folded into per-batch projection matrix M
    l2norms<<<2048, 256, 0, stream>>>(qkv, norms);
    qk_partial<<<256, 256, 0, stream>>>(qkv, Spart);
    softmax_M<<<64, 256, 0, stream>>>(Spart, norms, temperature, attn_proj, Mb16);
    // K4: x2 = x + M_b @ v
    mv_res_mfma<<<2048, 256, 0, stream>>>(qkv, Mb16, x, x2);
    // K5: t = pin_w @ LN2(x2)
    ln_gemm_mfma<256, ushort><<<2048, 256, 0, stream>>>(x2, pin_wb, ln2_w, ln2_b, t);
    // K6/K7 fused + gating: gated = [gelu(t*c1)*dw3(t) ; gelu(t*c1)*dw5(t)]
    dw_gated<<<dim3(256, 8), 256, 0, stream>>>(t, c3_w, c5_w, c1_w, gated);
    // K8: out = x2 + pout @ gated
    gdfn_mfma<<<2048, 256, 0, stream>>>(gated, x2, pout_wb, out);
}